// Round 1
// baseline (499.367 us; speedup 1.0000x reference)
//
#include <hip/hip_runtime.h>
#include <hip/hip_bf16.h>

#define S_LEN 2048
#define HIDV  3072
#define NHQ   24
#define NKVH  8
#define HDIM  128

typedef __bf16 bf16x8 __attribute__((ext_vector_type(8)));
typedef float  f32x4  __attribute__((ext_vector_type(4)));
typedef int    i32x4  __attribute__((ext_vector_type(4)));

__device__ __forceinline__ void gload_lds16(const void* g, void* l) {
    __builtin_amdgcn_global_load_lds((__attribute__((address_space(1))) void*)g,
                                     (__attribute__((address_space(3))) void*)l, 16, 0, 0);
}

// ---------------- cast f32 -> bf16, 4 elems/thread ----------------
__global__ void cast_f32_bf16(const float* __restrict__ in, __hip_bfloat16* __restrict__ out, int n) {
    int i = (blockIdx.x * blockDim.x + threadIdx.x) * 4;
    if (i >= n) return;
    float4 v = *(const float4*)(in + i);
    union { __hip_bfloat16 h[4]; ushort4 u; } pk;
    pk.h[0] = __float2bfloat16(v.x);
    pk.h[1] = __float2bfloat16(v.y);
    pk.h[2] = __float2bfloat16(v.z);
    pk.h[3] = __float2bfloat16(v.w);
    *(ushort4*)(out + i) = pk.u;
}

// ---------------- GEMM: C[M,N] = A[M,K] * B[N,K]^T (bf16 in, f32 acc) ----------------
// MODE 0: store f32 to C[row*N+col].  MODE 1: store bf16 transposed to C[col*M+row].
template<int MODE>
__global__ void gemm_bt(const __hip_bfloat16* __restrict__ A,
                        const __hip_bfloat16* __restrict__ B,
                        void* __restrict__ Cv, int M, int N, int K)
{
    __shared__ __hip_bfloat16 As[128 * 32];
    __shared__ __hip_bfloat16 Bs[128 * 32];
    const int tid = threadIdx.x;
    const int w    = tid >> 6;
    const int lane = tid & 63;
    const int lr = lane & 15, lg = lane >> 4;
    const int bm = blockIdx.y, bn = blockIdx.x;
    const int wr = w >> 1, wc = w & 1;
    const int sm = lane >> 2, sk8 = lane & 3;

    f32x4 zf = {0.f, 0.f, 0.f, 0.f};
    f32x4 acc[4][4];
#pragma unroll
    for (int i = 0; i < 4; ++i)
#pragma unroll
        for (int j = 0; j < 4; ++j) acc[i][j] = zf;

    const __hip_bfloat16* Abase = A + (size_t)(bm * 128) * K;
    const __hip_bfloat16* Bbase = B + (size_t)(bn * 128) * K;

    for (int k0 = 0; k0 < K; k0 += 32) {
#pragma unroll
        for (int t = 0; t < 2; ++t) {
            int seg = w + 4 * t;
            int m = seg * 16 + sm;
            gload_lds16(Abase + (size_t)m * K + k0 + sk8 * 8, As + m * 32 + sk8 * 8);
            gload_lds16(Bbase + (size_t)m * K + k0 + sk8 * 8, Bs + m * 32 + sk8 * 8);
        }
        __syncthreads();
        bf16x8 af[4], bfr[4];
#pragma unroll
        for (int i = 0; i < 4; ++i) {
            af[i]  = *(const bf16x8*)(As + (wr * 64 + i * 16 + lr) * 32 + lg * 8);
            bfr[i] = *(const bf16x8*)(Bs + (wc * 64 + i * 16 + lr) * 32 + lg * 8);
        }
#pragma unroll
        for (int mi = 0; mi < 4; ++mi)
#pragma unroll
            for (int ni = 0; ni < 4; ++ni)
                acc[mi][ni] = __builtin_amdgcn_mfma_f32_16x16x32_bf16(af[mi], bfr[ni], acc[mi][ni], 0, 0, 0);
        __syncthreads();
    }

#pragma unroll
    for (int mi = 0; mi < 4; ++mi)
#pragma unroll
        for (int ni = 0; ni < 4; ++ni)
#pragma unroll
            for (int j = 0; j < 4; ++j) {
                int row = bm * 128 + wr * 64 + mi * 16 + lg * 4 + j;
                int col = bn * 128 + wc * 64 + ni * 16 + lr;
                if (MODE == 0)
                    ((float*)Cv)[(size_t)row * N + col] = acc[mi][ni][j];
                else
                    ((__hip_bfloat16*)Cv)[(size_t)col * M + row] = __float2bfloat16(acc[mi][ni][j]);
            }
}

// ---------------- RMSNorm + RoPE: one wave per (s, h) row of 128 ----------------
__global__ void norm_rope_kernel(const float* __restrict__ in, __hip_bfloat16* __restrict__ out,
                                 const float* __restrict__ nw, const float* __restrict__ cosp,
                                 const float* __restrict__ sinp, int H, int so_s, int so_h)
{
    int gw = blockIdx.x * 4 + (threadIdx.x >> 6);
    int lane = threadIdx.x & 63;
    int s = gw / H, h = gw - s * H;
    const float* row = in + (size_t)s * (H * HDIM) + h * HDIM;
    float x1 = row[lane], x2 = row[lane + 64];
    float ss = x1 * x1 + x2 * x2;
#pragma unroll
    for (int xm = 1; xm < 64; xm <<= 1) ss += __shfl_xor(ss, xm, 64);
    float rs = rsqrtf(ss * (1.f / 128.f) + 1e-6f);
    float n1 = x1 * rs * (1.f + nw[lane]);
    float n2 = x2 * rs * (1.f + nw[lane + 64]);
    float c1 = cosp[s * HDIM + lane], c2 = cosp[s * HDIM + lane + 64];
    float s1 = sinp[s * HDIM + lane], s2 = sinp[s * HDIM + lane + 64];
    out[(size_t)h * so_h + (size_t)s * so_s + lane]      = __float2bfloat16(n1 * c1 - n2 * s1);
    out[(size_t)h * so_h + (size_t)s * so_s + lane + 64] = __float2bfloat16(n2 * c2 + n1 * s2);
}

// ---------------- Flash attention, causal, GQA 3:1, tanh softcap ----------------
// Q: [S][NHQ*HDIM] bf16; Kc: [NKVH][S][HDIM] bf16; Vt: [NKVH][HDIM][S] bf16; O: [S][NHQ*HDIM] bf16
__global__ __launch_bounds__(256) void attn_kernel(
    const __hip_bfloat16* __restrict__ Q,
    const __hip_bfloat16* __restrict__ Kc,
    const __hip_bfloat16* __restrict__ Vt,
    __hip_bfloat16* __restrict__ O)
{
    __shared__ __hip_bfloat16 Ks[64 * 128];   // [kvpos][d], xor-swizzled
    __shared__ __hip_bfloat16 Vs[128 * 64];   // [d][kvpos], xor-swizzled
    __shared__ __hip_bfloat16 Ps[4][16 * 72]; // per-wave P tile, padded rows

    const int qt = blockIdx.x;
    const int h  = blockIdx.y;
    const int kh = h / (NHQ / NKVH);
    const int tid = threadIdx.x;
    const int w = tid >> 6;
    const int lane = tid & 63;
    const int lr = lane & 15, lg = lane >> 4;
    const int q0 = qt * 64;
    const int qrow_base = q0 + w * 16;

    bf16x8 aq[4];
    {
        const __hip_bfloat16* qp = Q + (size_t)(qrow_base + lr) * HIDV + h * HDIM + lg * 8;
#pragma unroll
        for (int ks = 0; ks < 4; ++ks) aq[ks] = *(const bf16x8*)(qp + ks * 32);
    }

    f32x4 zf = {0.f, 0.f, 0.f, 0.f};
    f32x4 oacc[8];
#pragma unroll
    for (int i = 0; i < 8; ++i) oacc[i] = zf;
    float mrow[4] = {-1e30f, -1e30f, -1e30f, -1e30f};
    float lrow[4] = {0.f, 0.f, 0.f, 0.f};

    const char* kg = (const char*)(Kc + (size_t)kh * S_LEN * HDIM);
    const char* vg = (const char*)(Vt + (size_t)kh * HDIM * S_LEN);

    for (int jt = 0; jt <= qt; ++jt) {
        const int j0 = jt * 64;
        // stage K tile [64][128] and V^T tile [128][64], both swizzled
#pragma unroll
        for (int i = 0; i < 4; ++i) {
            int c = tid + 256 * i;
            int krow = c >> 4, kcb = (c & 15) * 16;
            i32x4 kvv = *(const i32x4*)(kg + (size_t)(j0 + krow) * 256 + kcb);
            *(i32x4*)((char*)Ks + ((krow * 256 + kcb) ^ ((krow & 7) << 4))) = kvv;
            int vrow = c >> 3, vcb = (c & 7) * 16;
            i32x4 vvv = *(const i32x4*)(vg + (size_t)vrow * (S_LEN * 2) + j0 * 2 + vcb);
            *(i32x4*)((char*)Vs + ((vrow * 128 + vcb) ^ ((vrow & 7) << 4))) = vvv;
        }
        __syncthreads();

        // S = Q K^T  (rows = q, cols = kv)
        f32x4 sf[4];
#pragma unroll
        for (int nf = 0; nf < 4; ++nf) {
            sf[nf] = zf;
            int row = nf * 16 + lr;
#pragma unroll
            for (int ks = 0; ks < 4; ++ks) {
                int boff = (row * 256 + (ks * 32 + lg * 8) * 2) ^ ((row & 7) << 4);
                bf16x8 bk = *(const bf16x8*)((const char*)Ks + boff);
                sf[nf] = __builtin_amdgcn_mfma_f32_16x16x32_bf16(aq[ks], bk, sf[nf], 0, 0, 0);
            }
        }

        const bool diag = (jt == qt);
        float z[4][4];
#pragma unroll
        for (int nf = 0; nf < 4; ++nf) {
            int jpos = j0 + nf * 16 + lr;
#pragma unroll
            for (int r = 0; r < 4; ++r) {
                float sv = sf[nf][r] * 0.0017677669529663688f; // SCALING / SOFTCAP
                float e2 = __expf(2.f * sv);
                float t = 50.f * ((e2 - 1.f) / (e2 + 1.f));
                if (diag && jpos > (qrow_base + lg * 4 + r)) t = -1e30f;
                z[nf][r] = t;
            }
        }
#pragma unroll
        for (int r = 0; r < 4; ++r) {
            float mx = fmaxf(fmaxf(z[0][r], z[1][r]), fmaxf(z[2][r], z[3][r]));
#pragma unroll
            for (int xm = 1; xm < 16; xm <<= 1) mx = fmaxf(mx, __shfl_xor(mx, xm, 64));
            float mn = fmaxf(mrow[r], mx);
            float sc = __expf(mrow[r] - mn);
            mrow[r] = mn;
            float rsum = 0.f;
#pragma unroll
            for (int nf = 0; nf < 4; ++nf) {
                float p = __expf(z[nf][r] - mn);
                z[nf][r] = p;
                rsum += p;
            }
#pragma unroll
            for (int xm = 1; xm < 16; xm <<= 1) rsum += __shfl_xor(rsum, xm, 64);
            lrow[r] = lrow[r] * sc + rsum;
#pragma unroll
            for (int df = 0; df < 8; ++df) oacc[df][r] *= sc;
        }

        // P -> LDS (per-wave, [16 q][64 k] padded to 72)
        __hip_bfloat16* pw = &Ps[w][0];
#pragma unroll
        for (int nf = 0; nf < 4; ++nf)
#pragma unroll
            for (int r = 0; r < 4; ++r)
                pw[(lg * 4 + r) * 72 + nf * 16 + lr] = __float2bfloat16(z[nf][r]);

        // O += P V
#pragma unroll
        for (int ks2 = 0; ks2 < 2; ++ks2) {
            bf16x8 ap = *(const bf16x8*)((const char*)pw + lr * 144 + (ks2 * 32 + lg * 8) * 2);
#pragma unroll
            for (int df = 0; df < 8; ++df) {
                int row = df * 16 + lr;
                int boff = (row * 128 + (ks2 * 32 + lg * 8) * 2) ^ ((row & 7) << 4);
                bf16x8 bv = *(const bf16x8*)((const char*)Vs + boff);
                oacc[df] = __builtin_amdgcn_mfma_f32_16x16x32_bf16(ap, bv, oacc[df], 0, 0, 0);
            }
        }
        __syncthreads();
    }

    // epilogue: normalize and store
#pragma unroll
    for (int r = 0; r < 4; ++r) {
        float inv = 1.f / lrow[r];
        size_t rowoff = (size_t)(qrow_base + lg * 4 + r) * HIDV + h * HDIM;
#pragma unroll
        for (int df = 0; df < 8; ++df)
            O[rowoff + df * 16 + lr] = __float2bfloat16(oacc[df][r] * inv);
    }
}

extern "C" void kernel_launch(void* const* d_in, const int* in_sizes, int n_in,
                              void* d_out, int out_size, void* d_ws, size_t ws_size,
                              hipStream_t stream) {
    const float* hs   = (const float*)d_in[0];
    const float* cosp = (const float*)d_in[1];
    const float* sinp = (const float*)d_in[2];
    // d_in[3] attention_mask — exactly causal, applied analytically in attn_kernel
    const float* wq  = (const float*)d_in[4];
    const float* wk  = (const float*)d_in[5];
    const float* wv  = (const float*)d_in[6];
    const float* wo  = (const float*)d_in[7];
    const float* qnw = (const float*)d_in[8];
    const float* knw = (const float*)d_in[9];
    float* out = (float*)d_out;

    char* ws = (char*)d_ws;
    __hip_bfloat16* hsb = (__hip_bfloat16*)(ws + 0);          // 2048x3072 bf16
    __hip_bfloat16* wqb = (__hip_bfloat16*)(ws + 12582912);   // 3072x3072 bf16
    __hip_bfloat16* wkb = (__hip_bfloat16*)(ws + 31457280);   // 1024x3072 bf16
    __hip_bfloat16* wvb = (__hip_bfloat16*)(ws + 37748736);   // 1024x3072 bf16
    __hip_bfloat16* wob = (__hip_bfloat16*)(ws + 44040192);   // 3072x3072 bf16
    float*          qf  = (float*)(ws + 62914560);            // 2048x3072 f32
    float*          kf  = (float*)(ws + 88080384);            // 2048x1024 f32
    __hip_bfloat16* qb  = (__hip_bfloat16*)(ws + 96468992);   // 2048x3072 bf16
    __hip_bfloat16* kb  = (__hip_bfloat16*)(ws + 109051904);  // [8][2048][128] bf16
    __hip_bfloat16* vbt = (__hip_bfloat16*)(ws + 113246208);  // [8][128][2048] bf16 (V^T)
    __hip_bfloat16* ob  = (__hip_bfloat16*)(ws + 117440512);  // 2048x3072 bf16

    cast_f32_bf16<<<6144, 256, 0, stream>>>(hs, hsb, 6291456);
    cast_f32_bf16<<<9216, 256, 0, stream>>>(wq, wqb, 9437184);
    cast_f32_bf16<<<3072, 256, 0, stream>>>(wk, wkb, 3145728);
    cast_f32_bf16<<<3072, 256, 0, stream>>>(wv, wvb, 3145728);
    cast_f32_bf16<<<9216, 256, 0, stream>>>(wo, wob, 9437184);

    gemm_bt<0><<<dim3(24, 16), 256, 0, stream>>>(hsb, wqb, qf,  2048, 3072, 3072);
    gemm_bt<0><<<dim3(8, 16),  256, 0, stream>>>(hsb, wkb, kf,  2048, 1024, 3072);
    gemm_bt<1><<<dim3(8, 16),  256, 0, stream>>>(hsb, wvb, vbt, 2048, 1024, 3072);

    norm_rope_kernel<<<12288, 256, 0, stream>>>(qf, qb, qnw, cosp, sinp, 24, 3072, 128);
    norm_rope_kernel<<<4096, 256, 0, stream>>>(kf, kb, knw, cosp, sinp, 8, 128, 262144);

    attn_kernel<<<dim3(32, 24), 256, 0, stream>>>(qb, kb, vbt, ob);

    gemm_bt<0><<<dim3(24, 16), 256, 0, stream>>>(ob, wob, out, 2048, 3072, 3072);
}

// Round 2
// 288.268 us; speedup vs baseline: 1.7323x; 1.7323x over previous
//
#include <hip/hip_runtime.h>
#include <hip/hip_bf16.h>

#define S_LEN 2048
#define HIDV  3072
#define NHQ   24
#define NKVH  8
#define HDIM  128

typedef __bf16 bf16x8 __attribute__((ext_vector_type(8)));
typedef float  f32x4  __attribute__((ext_vector_type(4)));
typedef int    i32x4  __attribute__((ext_vector_type(4)));

__device__ __forceinline__ void gload_lds16(const void* g, void* l) {
    __builtin_amdgcn_global_load_lds((__attribute__((address_space(1))) void*)g,
                                     (__attribute__((address_space(3))) void*)l, 16, 0, 0);
}

// ---------------- cast f32 -> bf16, 4 elems/thread ----------------
__global__ void cast_f32_bf16(const float* __restrict__ in, __hip_bfloat16* __restrict__ out, int n) {
    int i = (blockIdx.x * blockDim.x + threadIdx.x) * 4;
    if (i >= n) return;
    float4 v = *(const float4*)(in + i);
    union { __hip_bfloat16 h[4]; ushort4 u; } pk;
    pk.h[0] = __float2bfloat16(v.x);
    pk.h[1] = __float2bfloat16(v.y);
    pk.h[2] = __float2bfloat16(v.z);
    pk.h[3] = __float2bfloat16(v.w);
    *(ushort4*)(out + i) = pk.u;
}

// ---------------- O-proj GEMM: C[M,N] f32 = A[M,K] * B[N,K]^T ----------------
__global__ void gemm_bt(const __hip_bfloat16* __restrict__ A,
                        const __hip_bfloat16* __restrict__ B,
                        float* __restrict__ C, int M, int N, int K)
{
    __shared__ __hip_bfloat16 As[128 * 32];
    __shared__ __hip_bfloat16 Bs[128 * 32];
    const int tid = threadIdx.x;
    const int w    = tid >> 6;
    const int lane = tid & 63;
    const int lr = lane & 15, lg = lane >> 4;
    const int bm = blockIdx.y, bn = blockIdx.x;
    const int wr = w >> 1, wc = w & 1;
    const int sm = lane >> 2, sk8 = lane & 3;

    f32x4 zf = {0.f, 0.f, 0.f, 0.f};
    f32x4 acc[4][4];
#pragma unroll
    for (int i = 0; i < 4; ++i)
#pragma unroll
        for (int j = 0; j < 4; ++j) acc[i][j] = zf;

    const __hip_bfloat16* Abase = A + (size_t)(bm * 128) * K;
    const __hip_bfloat16* Bbase = B + (size_t)(bn * 128) * K;

    for (int k0 = 0; k0 < K; k0 += 32) {
#pragma unroll
        for (int t = 0; t < 2; ++t) {
            int m = (w + 4 * t) * 16 + sm;
            gload_lds16(Abase + (size_t)m * K + k0 + sk8 * 8, As + m * 32 + sk8 * 8);
            gload_lds16(Bbase + (size_t)m * K + k0 + sk8 * 8, Bs + m * 32 + sk8 * 8);
        }
        __syncthreads();
        bf16x8 af[4], bfr[4];
#pragma unroll
        for (int i = 0; i < 4; ++i) {
            af[i]  = *(const bf16x8*)(As + (wr * 64 + i * 16 + lr) * 32 + lg * 8);
            bfr[i] = *(const bf16x8*)(Bs + (wc * 64 + i * 16 + lr) * 32 + lg * 8);
        }
#pragma unroll
        for (int mi = 0; mi < 4; ++mi)
#pragma unroll
            for (int ni = 0; ni < 4; ++ni)
                acc[mi][ni] = __builtin_amdgcn_mfma_f32_16x16x32_bf16(af[mi], bfr[ni], acc[mi][ni], 0, 0, 0);
        __syncthreads();
    }

#pragma unroll
    for (int mi = 0; mi < 4; ++mi)
#pragma unroll
        for (int ni = 0; ni < 4; ++ni)
#pragma unroll
            for (int j = 0; j < 4; ++j) {
                int row = bm * 128 + wr * 64 + mi * 16 + lg * 4 + j;
                int col = bn * 128 + wc * 64 + ni * 16 + lr;
                C[(size_t)row * N + col] = acc[mi][ni][j];
            }
}

// ---------------- fused QKV GEMM: A[2048,3072] x Wf[5120,3072]^T ----------------
// cols [0,3072) -> qf f32; [3072,4096) -> kf f32; [4096,5120) -> vbt bf16 transposed [col][row]
__global__ void gemm_qkv(const __hip_bfloat16* __restrict__ A,
                         const __hip_bfloat16* __restrict__ B,
                         float* __restrict__ qout, float* __restrict__ kout,
                         __hip_bfloat16* __restrict__ vout)
{
    const int K = 3072;
    __shared__ __hip_bfloat16 As[128 * 32];
    __shared__ __hip_bfloat16 Bs[128 * 32];
    const int tid = threadIdx.x;
    const int w    = tid >> 6;
    const int lane = tid & 63;
    const int lr = lane & 15, lg = lane >> 4;
    const int bm = blockIdx.y, bn = blockIdx.x;
    const int wr = w >> 1, wc = w & 1;
    const int sm = lane >> 2, sk8 = lane & 3;

    f32x4 zf = {0.f, 0.f, 0.f, 0.f};
    f32x4 acc[4][4];
#pragma unroll
    for (int i = 0; i < 4; ++i)
#pragma unroll
        for (int j = 0; j < 4; ++j) acc[i][j] = zf;

    const __hip_bfloat16* Abase = A + (size_t)(bm * 128) * K;
    const __hip_bfloat16* Bbase = B + (size_t)(bn * 128) * K;

    for (int k0 = 0; k0 < K; k0 += 32) {
#pragma unroll
        for (int t = 0; t < 2; ++t) {
            int m = (w + 4 * t) * 16 + sm;
            gload_lds16(Abase + (size_t)m * K + k0 + sk8 * 8, As + m * 32 + sk8 * 8);
            gload_lds16(Bbase + (size_t)m * K + k0 + sk8 * 8, Bs + m * 32 + sk8 * 8);
        }
        __syncthreads();
        bf16x8 af[4], bfr[4];
#pragma unroll
        for (int i = 0; i < 4; ++i) {
            af[i]  = *(const bf16x8*)(As + (wr * 64 + i * 16 + lr) * 32 + lg * 8);
            bfr[i] = *(const bf16x8*)(Bs + (wc * 64 + i * 16 + lr) * 32 + lg * 8);
        }
#pragma unroll
        for (int mi = 0; mi < 4; ++mi)
#pragma unroll
            for (int ni = 0; ni < 4; ++ni)
                acc[mi][ni] = __builtin_amdgcn_mfma_f32_16x16x32_bf16(af[mi], bfr[ni], acc[mi][ni], 0, 0, 0);
        __syncthreads();
    }

    // block-uniform segment: bn<24 -> Q, bn<32 -> K, else V
#pragma unroll
    for (int mi = 0; mi < 4; ++mi)
#pragma unroll
        for (int ni = 0; ni < 4; ++ni) {
            int row0 = bm * 128 + wr * 64 + mi * 16 + lg * 4;
            int col  = bn * 128 + wc * 64 + ni * 16 + lr;
            if (bn < 24) {
#pragma unroll
                for (int j = 0; j < 4; ++j)
                    qout[(size_t)(row0 + j) * 3072 + col] = acc[mi][ni][j];
            } else if (bn < 32) {
#pragma unroll
                for (int j = 0; j < 4; ++j)
                    kout[(size_t)(row0 + j) * 1024 + (col - 3072)] = acc[mi][ni][j];
            } else {
                union { __hip_bfloat16 h[4]; ushort4 u; } pk;
#pragma unroll
                for (int j = 0; j < 4; ++j) pk.h[j] = __float2bfloat16(acc[mi][ni][j]);
                *(ushort4*)(vout + (size_t)(col - 4096) * 2048 + row0) = pk.u;
            }
        }
}

// ---------------- RMSNorm + RoPE: one wave per (s, h) row of 128 ----------------
__global__ void norm_rope_kernel(const float* __restrict__ in, __hip_bfloat16* __restrict__ out,
                                 const float* __restrict__ nw, const float* __restrict__ cosp,
                                 const float* __restrict__ sinp, int H, int so_s, int so_h)
{
    int gw = blockIdx.x * 4 + (threadIdx.x >> 6);
    int lane = threadIdx.x & 63;
    int s = gw / H, h = gw - s * H;
    const float* row = in + (size_t)s * (H * HDIM) + h * HDIM;
    float x1 = row[lane], x2 = row[lane + 64];
    float ss = x1 * x1 + x2 * x2;
#pragma unroll
    for (int xm = 1; xm < 64; xm <<= 1) ss += __shfl_xor(ss, xm, 64);
    float rs = rsqrtf(ss * (1.f / 128.f) + 1e-6f);
    float n1 = x1 * rs * (1.f + nw[lane]);
    float n2 = x2 * rs * (1.f + nw[lane + 64]);
    float c1 = cosp[s * HDIM + lane], c2 = cosp[s * HDIM + lane + 64];
    float s1 = sinp[s * HDIM + lane], s2 = sinp[s * HDIM + lane + 64];
    out[(size_t)h * so_h + (size_t)s * so_s + lane]      = __float2bfloat16(n1 * c1 - n2 * s1);
    out[(size_t)h * so_h + (size_t)s * so_s + lane + 64] = __float2bfloat16(n2 * c2 + n1 * s2);
}

// ---------------- Flash attention: causal, GQA 3:1, tanh softcap, fixed-max softmax ----
// 128 threads / 2 waves. Block pb handles q half-tiles {pb, 63-pb} (32 rows each) -> 33
// kv-tile iterations per block, perfectly balanced.
__global__ __launch_bounds__(128) void attn_kernel(
    const __hip_bfloat16* __restrict__ Q,
    const __hip_bfloat16* __restrict__ Kc,
    const __hip_bfloat16* __restrict__ Vt,
    __hip_bfloat16* __restrict__ O)
{
    __shared__ __hip_bfloat16 Ks[64 * 128];   // [kv][d], xor-swizzled rows of 256B
    __shared__ __hip_bfloat16 Vs[128 * 64];   // [d][kv], xor-swizzled rows of 128B
    __shared__ __hip_bfloat16 Ps[2][16 * 72]; // per-wave P tile

    const int pb = blockIdx.x;  // 0..31
    const int h  = blockIdx.y;
    const int kh = h / (NHQ / NKVH);
    const int tid = threadIdx.x;
    const int w = tid >> 6;
    const int lane = tid & 63;
    const int lr = lane & 15, lg = lane >> 4;

    const char* kg = (const char*)(Kc + (size_t)kh * S_LEN * HDIM);
    const char* vg = (const char*)(Vt + (size_t)kh * HDIM * S_LEN);

    for (int half = 0; half < 2; ++half) {
        const int hb = half ? (63 - pb) : pb;
        const int q0 = hb * 32;
        const int qrow = q0 + w * 16;
        const int jtmax = (q0 + 31) >> 6;

        bf16x8 aq[4];
        {
            const __hip_bfloat16* qp = Q + (size_t)(qrow + lr) * HIDV + h * HDIM + lg * 8;
#pragma unroll
            for (int ks = 0; ks < 4; ++ks) aq[ks] = *(const bf16x8*)(qp + ks * 32);
        }

        f32x4 zf = {0.f, 0.f, 0.f, 0.f};
        f32x4 oacc[8];
#pragma unroll
        for (int i = 0; i < 8; ++i) oacc[i] = zf;
        float lacc[4] = {0.f, 0.f, 0.f, 0.f};

        for (int jt = 0; jt <= jtmax; ++jt) {
            const int j0 = jt * 64;
            // stage K tile (pre-swizzled global source, linear LDS dest)
#pragma unroll
            for (int i = 0; i < 8; ++i) {
                int base = (w * 8 + i) * 1024;
                int L = base + lane * 16;
                int row = L >> 8, c = L & 255;
                gload_lds16(kg + (size_t)(j0 + row) * 256 + (c ^ ((row & 7) << 4)),
                            (char*)Ks + base);
            }
            // stage V^T tile
#pragma unroll
            for (int i = 0; i < 8; ++i) {
                int base = (w * 8 + i) * 1024;
                int L = base + lane * 16;
                int row = L >> 7, c = L & 127;
                gload_lds16(vg + (size_t)row * (S_LEN * 2) + j0 * 2 + (c ^ ((row & 7) << 4)),
                            (char*)Vs + base);
            }
            __syncthreads();

            // S = Q K^T
            f32x4 sf[4];
#pragma unroll
            for (int nf = 0; nf < 4; ++nf) {
                sf[nf] = zf;
                int row = nf * 16 + lr;
#pragma unroll
                for (int ks = 0; ks < 4; ++ks) {
                    int boff = (row * 256 + ks * 64 + lg * 16) ^ ((row & 7) << 4);
                    bf16x8 bk = *(const bf16x8*)((const char*)Ks + boff);
                    sf[nf] = __builtin_amdgcn_mfma_f32_16x16x32_bf16(aq[ks], bk, sf[nf], 0, 0, 0);
                }
            }

            // softcap -> p = exp(50*tanh(s*scl/50) - 30), fixed max (softcap bounds |t|<=50)
            const bool diag = (jt == jtmax);
            __hip_bfloat16* pw = &Ps[w][0];
#pragma unroll
            for (int nf = 0; nf < 4; ++nf) {
                int jpos = j0 + nf * 16 + lr;
#pragma unroll
                for (int r = 0; r < 4; ++r) {
                    float e2 = __expf(sf[nf][r] * 0.0035355339059327376f); // 2*SCALING/SOFTCAP
                    float rr = __builtin_amdgcn_rcpf(e2 + 1.f);
                    float p  = __expf(fmaf(rr, -100.f, 20.f));
                    if (diag && jpos > (qrow + lg * 4 + r)) p = 0.f;
                    lacc[r] += p;
                    pw[(lg * 4 + r) * 72 + nf * 16 + lr] = __float2bfloat16(p);
                }
            }

            // O += P V
#pragma unroll
            for (int ks2 = 0; ks2 < 2; ++ks2) {
                bf16x8 ap = *(const bf16x8*)((const char*)pw + lr * 144 + ks2 * 64 + lg * 16);
#pragma unroll
                for (int df = 0; df < 8; ++df) {
                    int row = df * 16 + lr;
                    int boff = (row * 128 + ks2 * 64 + lg * 16) ^ ((row & 7) << 4);
                    bf16x8 bv = *(const bf16x8*)((const char*)Vs + boff);
                    oacc[df] = __builtin_amdgcn_mfma_f32_16x16x32_bf16(ap, bv, oacc[df], 0, 0, 0);
                }
            }
            __syncthreads();
        }

        // epilogue: reduce l over the 16-lane row group, normalize, store
#pragma unroll
        for (int r = 0; r < 4; ++r) {
            float t = lacc[r];
#pragma unroll
            for (int xm = 1; xm < 16; xm <<= 1) t += __shfl_xor(t, xm, 64);
            float inv = __builtin_amdgcn_rcpf(t);
            size_t rowoff = (size_t)(qrow + lg * 4 + r) * HIDV + h * HDIM;
#pragma unroll
            for (int df = 0; df < 8; ++df)
                O[rowoff + df * 16 + lr] = __float2bfloat16(oacc[df][r] * inv);
        }
    }
}

extern "C" void kernel_launch(void* const* d_in, const int* in_sizes, int n_in,
                              void* d_out, int out_size, void* d_ws, size_t ws_size,
                              hipStream_t stream) {
    const float* hs   = (const float*)d_in[0];
    const float* cosp = (const float*)d_in[1];
    const float* sinp = (const float*)d_in[2];
    // d_in[3] attention_mask — exactly causal, applied analytically in attn_kernel
    const float* wq  = (const float*)d_in[4];
    const float* wk  = (const float*)d_in[5];
    const float* wv  = (const float*)d_in[6];
    const float* wo  = (const float*)d_in[7];
    const float* qnw = (const float*)d_in[8];
    const float* knw = (const float*)d_in[9];
    float* out = (float*)d_out;

    char* ws = (char*)d_ws;
    __hip_bfloat16* hsb = (__hip_bfloat16*)(ws + 0);          // 2048x3072 bf16
    __hip_bfloat16* wf  = (__hip_bfloat16*)(ws + 12582912);   // 5120x3072 bf16 fused QKV weight
    __hip_bfloat16* wob = (__hip_bfloat16*)(ws + 44040192);   // 3072x3072 bf16
    float*          qf  = (float*)(ws + 62914560);            // 2048x3072 f32
    float*          kf  = (float*)(ws + 88080384);            // 2048x1024 f32
    __hip_bfloat16* qb  = (__hip_bfloat16*)(ws + 96468992);   // 2048x3072 bf16
    __hip_bfloat16* kb  = (__hip_bfloat16*)(ws + 109051904);  // [8][2048][128] bf16
    __hip_bfloat16* vbt = (__hip_bfloat16*)(ws + 113246208);  // [8][128][2048] bf16 (V^T)
    __hip_bfloat16* ob  = (__hip_bfloat16*)(ws + 117440512);  // 2048x3072 bf16

    cast_f32_bf16<<<6144, 256, 0, stream>>>(hs, hsb, 6291456);
    cast_f32_bf16<<<9216, 256, 0, stream>>>(wq, wf, 9437184);
    cast_f32_bf16<<<3072, 256, 0, stream>>>(wk, wf + 9437184, 3145728);
    cast_f32_bf16<<<3072, 256, 0, stream>>>(wv, wf + 12582912, 3145728);
    cast_f32_bf16<<<9216, 256, 0, stream>>>(wo, wob, 9437184);

    gemm_qkv<<<dim3(40, 16), 256, 0, stream>>>(hsb, wf, qf, kf, vbt);

    norm_rope_kernel<<<12288, 256, 0, stream>>>(qf, qb, qnw, cosp, sinp, 24, 3072, 128);
    norm_rope_kernel<<<4096, 256, 0, stream>>>(kf, kb, knw, cosp, sinp, 8, 128, 262144);

    attn_kernel<<<dim3(32, 24), 128, 0, stream>>>(qb, kb, vbt, ob);

    gemm_bt<<<dim3(24, 16), 256, 0, stream>>>(ob, wob, out, 2048, 3072, 3072);
}